// Round 3
// baseline (306.448 us; speedup 1.0000x reference)
//
#include <hip/hip_runtime.h>

#define BATCH_L 524288
#define NL 40
#define NXL 20
#define BLOCK 256
#define GRID 2048
#define NTHREADS (GRID * BLOCK)                    // 524288
#define NHALF (BATCH_L * 2)                        // 1048576 half-rows
#define ITERS (NHALF / NTHREADS)                   // 2 per thread

// One thread owns one half-row (20 floats = 5 float4). The Lorenz-96 periodic
// stencil needs only 3 floats from the OTHER half of the same row, which lane
// t^1 owns -> __shfl_xor. No LDS staging, no barriers before the reduction:
// all 15 vmem loads per thread are independent -> max loads in flight.
__global__ __launch_bounds__(BLOCK, 6) void hybrid_loss_main(
    const float4* __restrict__ pred4,
    const float4* __restrict__ targ4,
    const float4* __restrict__ ycur4,
    double* __restrict__ partials)     // [GRID][2]
{
    const int t = blockIdx.x * BLOCK + threadIdx.x;
    const int h = threadIdx.x & 1;     // 0 => cols 0..19 (observed, has targ term)
    float sdd = 0.f, spi = 0.f;

    for (int it = 0; it < ITERS; ++it) {
        const size_t H = (size_t)t + (size_t)it * NTHREADS;  // half-row index
        const size_t c0 = 5 * H;                             // first float4 chunk

        float4 pc[5], yc[5], tc[5];
#pragma unroll
        for (int k = 0; k < 5; ++k) pc[k] = pred4[c0 + k];
#pragma unroll
        for (int k = 0; k < 5; ++k) yc[k] = ycur4[c0 + k];
        if (h == 0) {
#pragma unroll
            for (int k = 0; k < 5; ++k) tc[k] = targ4[c0 + k];
        }

        float p[20];
#pragma unroll
        for (int k = 0; k < 5; ++k) {
            p[4 * k + 0] = pc[k].x; p[4 * k + 1] = pc[k].y;
            p[4 * k + 2] = pc[k].z; p[4 * k + 3] = pc[k].w;
        }

        // a_i = (p_i - y_i)/dt - (-p_i + F) = 101 p_i - 100 y_i - 8
        float A[20];
#pragma unroll
        for (int k = 0; k < 5; ++k) {
            A[4 * k + 0] = 101.f * pc[k].x - 100.f * yc[k].x - 8.f;
            A[4 * k + 1] = 101.f * pc[k].y - 100.f * yc[k].y - 8.f;
            A[4 * k + 2] = 101.f * pc[k].z - 100.f * yc[k].z - 8.f;
            A[4 * k + 3] = 101.f * pc[k].w - 100.f * yc[k].w - 8.f;
        }

        // Data-driven MSE: only the cols-0..19 half.
        if (h == 0) {
#pragma unroll
            for (int k = 0; k < 5; ++k) {
                const float d0 = pc[k].x - tc[k].x;
                const float d1 = pc[k].y - tc[k].y;
                const float d2 = pc[k].z - tc[k].z;
                const float d3 = pc[k].w - tc[k].w;
                sdd += d0 * d0 + d1 * d1 + d2 * d2 + d3 * d3;
            }
        }

        // Boundary exchange with the partner half (lane t^1):
        //   prev2 = partner p[18], prev1 = partner p[19], nxt = partner p[0]
        const float prev2 = __shfl_xor(p[18], 1);
        const float prev1 = __shfl_xor(p[19], 1);
        const float nxt   = __shfl_xor(p[0], 1);

        // d_i = A_i - (p_{i+1} - p_{i-2}) * p_{i-1}  (periodic, local indices)
        {
            float d = A[0] - (p[1] - prev2) * prev1;
            spi += d * d;
            d = A[1] - (p[2] - prev1) * p[0];
            spi += d * d;
#pragma unroll
            for (int i = 2; i <= 18; ++i) {
                d = A[i] - (p[i + 1] - p[i - 2]) * p[i - 1];
                spi += d * d;
            }
            d = A[19] - (nxt - p[17]) * p[18];
            spi += d * d;
        }
    }

    // Wave shuffle reduction in double -> LDS -> per-block partial.
    double sd = (double)sdd, sp = (double)spi;
#pragma unroll
    for (int off = 32; off > 0; off >>= 1) {
        sd += __shfl_down(sd, off, 64);
        sp += __shfl_down(sp, off, 64);
    }
    __shared__ double lds_red[2 * (BLOCK / 64)];
    const int lane = threadIdx.x & 63;
    const int wave = threadIdx.x >> 6;
    if (lane == 0) { lds_red[2 * wave] = sd; lds_red[2 * wave + 1] = sp; }
    __syncthreads();
    if (threadIdx.x == 0) {
        double tsd = 0.0, tsp = 0.0;
#pragma unroll
        for (int w = 0; w < BLOCK / 64; ++w) {
            tsd += lds_red[2 * w];
            tsp += lds_red[2 * w + 1];
        }
        partials[2 * blockIdx.x]     = tsd;   // every slot written every launch
        partials[2 * blockIdx.x + 1] = tsp;
    }
}

__global__ __launch_bounds__(256) void hybrid_loss_finalize(
    const double* __restrict__ partials, float* __restrict__ out)
{
    const double2* __restrict__ p2 = reinterpret_cast<const double2*>(partials);
    double sd = 0.0, sp = 0.0;
    for (int m = threadIdx.x; m < GRID; m += 256) {
        const double2 v = p2[m];
        sd += v.x; sp += v.y;
    }
#pragma unroll
    for (int off = 32; off > 0; off >>= 1) {
        sd += __shfl_down(sd, off, 64);
        sp += __shfl_down(sp, off, 64);
    }
    __shared__ double lds[8];
    const int lane = threadIdx.x & 63;
    const int wave = threadIdx.x >> 6;
    if (lane == 0) { lds[2 * wave] = sd; lds[2 * wave + 1] = sp; }
    __syncthreads();
    if (threadIdx.x == 0) {
        double tsd = 0.0, tsp = 0.0;
#pragma unroll
        for (int w = 0; w < 4; ++w) { tsd += lds[2 * w]; tsp += lds[2 * w + 1]; }
        const double l_dd = tsd / ((double)BATCH_L * NXL);
        const double l_pi = tsp / ((double)BATCH_L * NL);
        out[0] = (float)(l_dd + 0.1 * l_pi);
        out[1] = (float)l_dd;
        out[2] = (float)l_pi;
    }
}

extern "C" void kernel_launch(void* const* d_in, const int* in_sizes, int n_in,
                              void* d_out, int out_size, void* d_ws, size_t ws_size,
                              hipStream_t stream) {
    const float4* pred = (const float4*)d_in[0];
    const float4* targ = (const float4*)d_in[1];
    const float4* ycur = (const float4*)d_in[2];
    double* partials = (double*)d_ws;          // GRID * 2 doubles = 32 KB
    float* out = (float*)d_out;

    hybrid_loss_main<<<GRID, BLOCK, 0, stream>>>(pred, targ, ycur, partials);
    hybrid_loss_finalize<<<1, 256, 0, stream>>>(partials, out);
}

// Round 4
// 240.215 us; speedup vs baseline: 1.2757x; 1.2757x over previous
//
#include <hip/hip_runtime.h>

#define BATCH_L 524288
#define NL 40
#define NXL 20
#define BLOCK 256
#define GRID 2048
#define NTHREADS (GRID * BLOCK)                    // 524288
#define NHALF (BATCH_L * 2)                        // 1048576 half-rows
#define ITERS (NHALF / NTHREADS)                   // 2 per thread

// One thread owns one half-row (20 floats = 5 float4). The periodic stencil
// needs only 3 floats from the other half, owned by lane t^1 -> __shfl_xor.
// No LDS staging, no barriers in the stream. ALL threads load their half-row
// of targ (HBM-free: every 128B line of targ has used bytes anyway) so every
// vmem instruction is fully coalesced; dd arithmetic is masked by h==0.
// NO launch_bounds VGPR cap — R3's (256,6) forced 220 MB of scratch spills.
__global__ void hybrid_loss_main(
    const float4* __restrict__ pred4,
    const float4* __restrict__ targ4,
    const float4* __restrict__ ycur4,
    double* __restrict__ partials)     // [GRID][2]
{
    const int t = blockIdx.x * BLOCK + threadIdx.x;
    const float ddmask = (threadIdx.x & 1) ? 0.f : 1.f;  // h==0 half has the dd term
    float sdd = 0.f, spi = 0.f;

    for (int it = 0; it < ITERS; ++it) {
        const size_t H = (size_t)t + (size_t)it * NTHREADS;  // half-row index
        const size_t c0 = 5 * H;                             // first float4 chunk

        // Issue all 15 independent, fully-coalesced loads up front.
        float4 pc[5], yc[5], tc[5];
#pragma unroll
        for (int k = 0; k < 5; ++k) pc[k] = pred4[c0 + k];
#pragma unroll
        for (int k = 0; k < 5; ++k) tc[k] = targ4[c0 + k];
#pragma unroll
        for (int k = 0; k < 5; ++k) yc[k] = ycur4[c0 + k];

        float p[20];
#pragma unroll
        for (int k = 0; k < 5; ++k) {
            p[4 * k + 0] = pc[k].x; p[4 * k + 1] = pc[k].y;
            p[4 * k + 2] = pc[k].z; p[4 * k + 3] = pc[k].w;
        }

        // Data-driven MSE (masked: only the cols 0..19 half contributes).
        float s = 0.f;
#pragma unroll
        for (int k = 0; k < 5; ++k) {
            const float d0 = pc[k].x - tc[k].x;
            const float d1 = pc[k].y - tc[k].y;
            const float d2 = pc[k].z - tc[k].z;
            const float d3 = pc[k].w - tc[k].w;
            s += d0 * d0 + d1 * d1 + d2 * d2 + d3 * d3;
        }
        sdd += ddmask * s;

        // Boundary exchange with the partner half (lane t^1).
        const float prev2 = __shfl_xor(p[18], 1);
        const float prev1 = __shfl_xor(p[19], 1);
        const float nxt   = __shfl_xor(p[0], 1);

        // d_i = (101 p_i - 100 y_i - 8) - (p_{i+1} - p_{i-2}) * p_{i-1}
        // (A folded inline — no A[20] array, keeps live VGPRs low.)
        const float* y = reinterpret_cast<const float*>(yc);
        {
            float d = (101.f * p[0] - 100.f * y[0] - 8.f) - (p[1] - prev2) * prev1;
            spi += d * d;
            d = (101.f * p[1] - 100.f * y[1] - 8.f) - (p[2] - prev1) * p[0];
            spi += d * d;
#pragma unroll
            for (int i = 2; i <= 18; ++i) {
                d = (101.f * p[i] - 100.f * y[i] - 8.f) - (p[i + 1] - p[i - 2]) * p[i - 1];
                spi += d * d;
            }
            d = (101.f * p[19] - 100.f * y[19] - 8.f) - (nxt - p[17]) * p[18];
            spi += d * d;
        }
    }

    // Wave shuffle reduction in double -> LDS -> per-block partial.
    double sd = (double)sdd, sp = (double)spi;
#pragma unroll
    for (int off = 32; off > 0; off >>= 1) {
        sd += __shfl_down(sd, off, 64);
        sp += __shfl_down(sp, off, 64);
    }
    __shared__ double lds_red[2 * (BLOCK / 64)];
    const int lane = threadIdx.x & 63;
    const int wave = threadIdx.x >> 6;
    if (lane == 0) { lds_red[2 * wave] = sd; lds_red[2 * wave + 1] = sp; }
    __syncthreads();
    if (threadIdx.x == 0) {
        double tsd = 0.0, tsp = 0.0;
#pragma unroll
        for (int w = 0; w < BLOCK / 64; ++w) {
            tsd += lds_red[2 * w];
            tsp += lds_red[2 * w + 1];
        }
        partials[2 * blockIdx.x]     = tsd;   // every slot written every launch
        partials[2 * blockIdx.x + 1] = tsp;
    }
}

__global__ __launch_bounds__(256) void hybrid_loss_finalize(
    const double* __restrict__ partials, float* __restrict__ out)
{
    const double2* __restrict__ p2 = reinterpret_cast<const double2*>(partials);
    double sd = 0.0, sp = 0.0;
    for (int m = threadIdx.x; m < GRID; m += 256) {
        const double2 v = p2[m];
        sd += v.x; sp += v.y;
    }
#pragma unroll
    for (int off = 32; off > 0; off >>= 1) {
        sd += __shfl_down(sd, off, 64);
        sp += __shfl_down(sp, off, 64);
    }
    __shared__ double lds[8];
    const int lane = threadIdx.x & 63;
    const int wave = threadIdx.x >> 6;
    if (lane == 0) { lds[2 * wave] = sd; lds[2 * wave + 1] = sp; }
    __syncthreads();
    if (threadIdx.x == 0) {
        double tsd = 0.0, tsp = 0.0;
#pragma unroll
        for (int w = 0; w < 4; ++w) { tsd += lds[2 * w]; tsp += lds[2 * w + 1]; }
        const double l_dd = tsd / ((double)BATCH_L * NXL);
        const double l_pi = tsp / ((double)BATCH_L * NL);
        out[0] = (float)(l_dd + 0.1 * l_pi);
        out[1] = (float)l_dd;
        out[2] = (float)l_pi;
    }
}

extern "C" void kernel_launch(void* const* d_in, const int* in_sizes, int n_in,
                              void* d_out, int out_size, void* d_ws, size_t ws_size,
                              hipStream_t stream) {
    const float4* pred = (const float4*)d_in[0];
    const float4* targ = (const float4*)d_in[1];
    const float4* ycur = (const float4*)d_in[2];
    double* partials = (double*)d_ws;          // GRID * 2 doubles = 32 KB
    float* out = (float*)d_out;

    hybrid_loss_main<<<GRID, BLOCK, 0, stream>>>(pred, targ, ycur, partials);
    hybrid_loss_finalize<<<1, 256, 0, stream>>>(partials, out);
}